// Round 5
// baseline (2246.017 us; speedup 1.0000x reference)
//
#include <hip/hip_runtime.h>
#include <hip/hip_fp16.h>
#include <stdint.h>

// HeteroscedasticSoftmax: out = mean_{s<100} softmax(logits + eps_s * exp(log_std), axis=C)
// eps reproduces jax.random.normal under the partitionable threefry scheme (verified R0-R2).
//
// R4 = R3 + NaN fix: the literal -2.99999994f rounds to -3.0f, so u hits exactly -1.0
// at bits==0 (p=2^-23, ~119 times per run) -> log(0) -> inf-inf = NaN. The fmax clamp
// (present in R0-R2, removed in R3) is REQUIRED. Restored.
//
// R3 structure kept: keys in d_ws via pre-kernel (wave-uniform scalar loads),
// (logit,std)*log2e packed f16x2 in LDS (19 KB/block -> 8 blocks/CU),
// __launch_bounds__(256,8) targeting 32 waves/CU.

#define NCH    19
#define HW     65536
#define NSAMP  100

__device__ __forceinline__ uint32_t rotl(uint32_t x, uint32_t r) {
  return __builtin_amdgcn_alignbit(x, x, 32u - r);
}

__device__ __forceinline__ void tf2x32_full(uint32_t k0, uint32_t k1,
                                            uint32_t x0, uint32_t x1,
                                            uint32_t& o0, uint32_t& o1) {
  const uint32_t k2 = k0 ^ k1 ^ 0x1BD11BDAu;
#define TFR(r) { x0 += x1; x1 = rotl(x1, r) ^ x0; }
  x0 += k0; x1 += k1;
  TFR(13u) TFR(15u) TFR(26u) TFR(6u)
  x0 += k1; x1 += k2 + 1u;
  TFR(17u) TFR(29u) TFR(16u) TFR(24u)
  x0 += k2; x1 += k0 + 2u;
  TFR(13u) TFR(15u) TFR(26u) TFR(6u)
  x0 += k0; x1 += k1 + 3u;
  TFR(17u) TFR(29u) TFR(16u) TFR(24u)
  x0 += k1; x1 += k2 + 4u;
  TFR(13u) TFR(15u) TFR(26u) TFR(6u)
  x0 += k2; x1 += k0 + 5u;
#undef TFR
  o0 = x0; o1 = x1;
}

// Hot-path threefry, x0_in = 0, returns o0^o1. Keys wave-uniform (SGPR).
__device__ __forceinline__ uint32_t tf_fold(uint32_t k0, uint32_t k1, uint32_t k2,
                                            uint32_t x1in) {
  uint32_t x0, x1;
  x1 = x1in + k1;
  x0 = k0 + x1;
  x1 = rotl(x1, 13u) ^ x0;
  x0 += x1; x1 = rotl(x1, 15u) ^ x0;
  x0 += x1; x1 = rotl(x1, 26u) ^ x0;
  x0 += x1; x1 = rotl(x1,  6u) ^ x0;
  x1 += k2 + 1u;
  x0 = x0 + k1 + x1; x1 = rotl(x1, 17u) ^ x0;
  x0 += x1; x1 = rotl(x1, 29u) ^ x0;
  x0 += x1; x1 = rotl(x1, 16u) ^ x0;
  x0 += x1; x1 = rotl(x1, 24u) ^ x0;
  x1 += k0 + 2u;
  x0 = x0 + k2 + x1; x1 = rotl(x1, 13u) ^ x0;
  x0 += x1; x1 = rotl(x1, 15u) ^ x0;
  x0 += x1; x1 = rotl(x1, 26u) ^ x0;
  x0 += x1; x1 = rotl(x1,  6u) ^ x0;
  x1 += k1 + 3u;
  x0 = x0 + k0 + x1; x1 = rotl(x1, 17u) ^ x0;
  x0 += x1; x1 = rotl(x1, 29u) ^ x0;
  x0 += x1; x1 = rotl(x1, 16u) ^ x0;
  x0 += x1; x1 = rotl(x1, 24u) ^ x0;
  x1 += k2 + 4u;
  x0 = x0 + k1 + x1; x1 = rotl(x1, 13u) ^ x0;
  x0 += x1; x1 = rotl(x1, 15u) ^ x0;
  x0 += x1; x1 = rotl(x1, 26u) ^ x0;
  x0 += x1; x1 = rotl(x1,  6u) ^ x0;
  return (x0 + k2) ^ (x1 + k0 + 5u);
}

// sqrt(2)*erfinv(u); central poly in t = log2(1-u^2) (ln2 + sqrt2 folded).
__device__ __forceinline__ float bits_to_eps(uint32_t bits) {
  const float lo = -0.99999994f;  // nextafter(-1, 0)
  float x = __uint_as_float((bits >> 9) | 0x3F800000u);
  // NOTE: the addend is exactly -3.0f after literal rounding, so u can hit -1.0
  // at bits==0; the clamp below is load-bearing (NaN guard), do not remove.
  float u = fmaf(x, 2.0f, -3.0f);
  u = fmaxf(u, lo);
  float t = __builtin_amdgcn_logf(fmaf(-u, u, 1.0f));  // log2(1-u^2) <= 0
  float p;
  if (t > -7.2135401f) {          // central: w = -ln2*t < 5
    float tw = t + 3.6067376f;
    p = 2.1176667e-09f;
    p = fmaf(p, tw, -3.7319753e-08f);
    p = fmaf(p, tw, -5.5262077e-07f);
    p = fmaf(p, tw, 9.9370361e-07f);
    p = fmaf(p, tw, 7.1355918e-05f);
    p = fmaf(p, tw, 5.9046852e-04f);
    p = fmaf(p, tw, -2.8386612e-03f);
    p = fmaf(p, tw, -2.4177230e-01f);
    p = fmaf(p, tw, 2.1233141e+00f);
  } else {                        // tail (~0.34% of lanes)
    float w = -0.69314718f * t;
    w = __fsqrt_rn(w) - 3.0f;
    p = -2.8314594e-04f;
    p = fmaf(p, w, 1.4276565e-04f);
    p = fmaf(p, w, 1.9082604e-03f);
    p = fmaf(p, w, -5.1950124e-03f);
    p = fmaf(p, w, 8.1168916e-03f);
    p = fmaf(p, w, -1.0779791e-02f);
    p = fmaf(p, w, 1.3348577e-02f);
    p = fmaf(p, w, 1.4165810e+00f);
    p = fmaf(p, w, 4.0064324e+00f);
  }
  return p * u;
}

__global__ void HS_keys_kernel(uint2* __restrict__ ks) {
  const int t = threadIdx.x;
  if (t < NSAMP) {
    uint32_t a, b;
    tf2x32_full(0u, 1u, 0u, (uint32_t)t, a, b);  // split of key(1)
    ks[t] = make_uint2(a, b);
  }
}

__global__ __launch_bounds__(256, 8)
void HeteroscedasticSoftmax_kernel(const float* __restrict__ in,
                                   float* __restrict__ out,
                                   const uint2* __restrict__ keys) {
  __shared__ __half2 sls[NCH][256];  // (logit*log2e, std*log2e) f16x2

  const int t   = threadIdx.x;
  const int gid = blockIdx.x * 256 + t;
  const int b_  = gid >> 16;
  const int hw  = gid & 65535;

  const float L2E = 1.4426950408889634f;
  const float* pin = in + (size_t)b_ * (2 * NCH * HW) + hw;
  float acc[NCH];
#pragma unroll
  for (int c = 0; c < NCH; ++c) {
    float lg = pin[c * HW] * L2E;
    float sd = __expf(pin[(NCH + c) * HW]) * L2E;
    sls[c][t] = __floats2half2_rn(lg, sd);
    acc[c] = 0.0f;
  }
  __syncthreads();

  const uint32_t jbase = (uint32_t)(b_ * NCH) * (uint32_t)HW + (uint32_t)hw;

#pragma unroll 1
  for (int s = 0; s < NSAMP; ++s) {
    const uint2 kk = keys[s];
    const uint32_t k0 = __builtin_amdgcn_readfirstlane(kk.x);
    const uint32_t k1 = __builtin_amdgcn_readfirstlane(kk.y);
    const uint32_t k2 = k0 ^ k1 ^ 0x1BD11BDAu;

    float z[NCH];
#pragma unroll
    for (int c = 0; c < NCH; ++c) {
      const uint32_t bits = tf_fold(k0, k1, k2, jbase + (uint32_t)c * HW);
      const float eps = bits_to_eps(bits);
      const __half2 h = sls[c][t];
      z[c] = fmaf(eps, __high2float(h), __low2float(h));  // (lg + eps*sd)*log2e
    }

    float m0 = fmaxf(z[0], z[1]),  m1 = fmaxf(z[2], z[3]);
    float m2 = fmaxf(z[4], z[5]),  m3 = fmaxf(z[6], z[7]);
    float m4 = fmaxf(z[8], z[9]),  m5 = fmaxf(z[10], z[11]);
    float m6 = fmaxf(z[12], z[13]), m7 = fmaxf(z[14], z[15]);
    float m8 = fmaxf(z[16], z[17]);
    m0 = fmaxf(m0, m1); m2 = fmaxf(m2, m3); m4 = fmaxf(m4, m5);
    m6 = fmaxf(m6, m7); m8 = fmaxf(m8, z[18]);
    m0 = fmaxf(m0, m2); m4 = fmaxf(m4, m6);
    m0 = fmaxf(m0, m4);
    const float m = fmaxf(m0, m8);

#pragma unroll
    for (int c = 0; c < NCH; ++c) z[c] = __builtin_amdgcn_exp2f(z[c] - m);

    float s0 = z[0] + z[1],  s1 = z[2] + z[3];
    float s2 = z[4] + z[5],  s3 = z[6] + z[7];
    float s4 = z[8] + z[9],  s5 = z[10] + z[11];
    float s6 = z[12] + z[13], s7 = z[14] + z[15];
    float s8 = z[16] + z[17];
    s0 += s1; s2 += s3; s4 += s5; s6 += s7; s8 += z[18];
    s0 += s2; s4 += s6;
    s0 += s4;
    const float r = __builtin_amdgcn_rcpf(s0 + s8);

#pragma unroll
    for (int c = 0; c < NCH; ++c) acc[c] = fmaf(z[c], r, acc[c]);
  }

  float* pout = out + (size_t)b_ * (NCH * HW) + hw;
#pragma unroll
  for (int c = 0; c < NCH; ++c) pout[c * HW] = acc[c] * 0.01f;
}

extern "C" void kernel_launch(void* const* d_in, const int* in_sizes, int n_in,
                              void* d_out, int out_size, void* d_ws, size_t ws_size,
                              hipStream_t stream) {
  const float* in = (const float*)d_in[0];
  float* out = (float*)d_out;
  uint2* keys = (uint2*)d_ws;  // 800 B of scratch
  HS_keys_kernel<<<1, 128, 0, stream>>>(keys);
  HeteroscedasticSoftmax_kernel<<<2048, 256, 0, stream>>>(in, out, keys);
}

// Round 6
// 2162.072 us; speedup vs baseline: 1.0388x; 1.0388x over previous
//
#include <hip/hip_runtime.h>
#include <hip/hip_fp16.h>
#include <stdint.h>

// HeteroscedasticSoftmax: out = mean_{s<100} softmax(logits + eps_s * exp(log_std), axis=C)
// eps reproduces jax.random.normal under the partitionable threefry scheme (verified R0-R2).
//
// R5 = R4 with __launch_bounds__(256,6) instead of (256,8).
// R4 post-mortem: (256,8) forced a 64-VGPR cap; allocator went to 32 VGPRs and
// spilled acc[19]+z[19] to scratch -> FETCH_SIZE 39->845 MB, 400 GB/s of HBM
// scratch thrash, net regression despite 62% occupancy. Live set is ~60 VGPRs;
// (256,6) gives an 85-VGPR budget -> spill-free at 24 waves/CU (75%).
// LDS 19.5 KB/block (f16x2 staging) allows 8 blocks/CU - not binding.

#define NCH    19
#define HW     65536
#define NSAMP  100

__device__ __forceinline__ uint32_t rotl(uint32_t x, uint32_t r) {
  return __builtin_amdgcn_alignbit(x, x, 32u - r);
}

__device__ __forceinline__ void tf2x32_full(uint32_t k0, uint32_t k1,
                                            uint32_t x0, uint32_t x1,
                                            uint32_t& o0, uint32_t& o1) {
  const uint32_t k2 = k0 ^ k1 ^ 0x1BD11BDAu;
#define TFR(r) { x0 += x1; x1 = rotl(x1, r) ^ x0; }
  x0 += k0; x1 += k1;
  TFR(13u) TFR(15u) TFR(26u) TFR(6u)
  x0 += k1; x1 += k2 + 1u;
  TFR(17u) TFR(29u) TFR(16u) TFR(24u)
  x0 += k2; x1 += k0 + 2u;
  TFR(13u) TFR(15u) TFR(26u) TFR(6u)
  x0 += k0; x1 += k1 + 3u;
  TFR(17u) TFR(29u) TFR(16u) TFR(24u)
  x0 += k1; x1 += k2 + 4u;
  TFR(13u) TFR(15u) TFR(26u) TFR(6u)
  x0 += k2; x1 += k0 + 5u;
#undef TFR
  o0 = x0; o1 = x1;
}

// Hot-path threefry, x0_in = 0, returns o0^o1. Keys wave-uniform (SGPR).
__device__ __forceinline__ uint32_t tf_fold(uint32_t k0, uint32_t k1, uint32_t k2,
                                            uint32_t x1in) {
  uint32_t x0, x1;
  x1 = x1in + k1;
  x0 = k0 + x1;
  x1 = rotl(x1, 13u) ^ x0;
  x0 += x1; x1 = rotl(x1, 15u) ^ x0;
  x0 += x1; x1 = rotl(x1, 26u) ^ x0;
  x0 += x1; x1 = rotl(x1,  6u) ^ x0;
  x1 += k2 + 1u;
  x0 = x0 + k1 + x1; x1 = rotl(x1, 17u) ^ x0;
  x0 += x1; x1 = rotl(x1, 29u) ^ x0;
  x0 += x1; x1 = rotl(x1, 16u) ^ x0;
  x0 += x1; x1 = rotl(x1, 24u) ^ x0;
  x1 += k0 + 2u;
  x0 = x0 + k2 + x1; x1 = rotl(x1, 13u) ^ x0;
  x0 += x1; x1 = rotl(x1, 15u) ^ x0;
  x0 += x1; x1 = rotl(x1, 26u) ^ x0;
  x0 += x1; x1 = rotl(x1,  6u) ^ x0;
  x1 += k1 + 3u;
  x0 = x0 + k0 + x1; x1 = rotl(x1, 17u) ^ x0;
  x0 += x1; x1 = rotl(x1, 29u) ^ x0;
  x0 += x1; x1 = rotl(x1, 16u) ^ x0;
  x0 += x1; x1 = rotl(x1, 24u) ^ x0;
  x1 += k2 + 4u;
  x0 = x0 + k1 + x1; x1 = rotl(x1, 13u) ^ x0;
  x0 += x1; x1 = rotl(x1, 15u) ^ x0;
  x0 += x1; x1 = rotl(x1, 26u) ^ x0;
  x0 += x1; x1 = rotl(x1,  6u) ^ x0;
  return (x0 + k2) ^ (x1 + k0 + 5u);
}

// sqrt(2)*erfinv(u); central poly in t = log2(1-u^2) (ln2 + sqrt2 folded).
__device__ __forceinline__ float bits_to_eps(uint32_t bits) {
  const float lo = -0.99999994f;  // nextafter(-1, 0)
  float x = __uint_as_float((bits >> 9) | 0x3F800000u);
  // The addend is exactly -3.0f after literal rounding, so u hits -1.0 at
  // bits==0; the clamp below is the NaN guard (R4 lesson) - do not remove.
  float u = fmaf(x, 2.0f, -3.0f);
  u = fmaxf(u, lo);
  float t = __builtin_amdgcn_logf(fmaf(-u, u, 1.0f));  // log2(1-u^2) <= 0
  float p;
  if (t > -7.2135401f) {          // central: w = -ln2*t < 5
    float tw = t + 3.6067376f;
    p = 2.1176667e-09f;
    p = fmaf(p, tw, -3.7319753e-08f);
    p = fmaf(p, tw, -5.5262077e-07f);
    p = fmaf(p, tw, 9.9370361e-07f);
    p = fmaf(p, tw, 7.1355918e-05f);
    p = fmaf(p, tw, 5.9046852e-04f);
    p = fmaf(p, tw, -2.8386612e-03f);
    p = fmaf(p, tw, -2.4177230e-01f);
    p = fmaf(p, tw, 2.1233141e+00f);
  } else {                        // tail (~0.34% of lanes)
    float w = -0.69314718f * t;
    w = __fsqrt_rn(w) - 3.0f;
    p = -2.8314594e-04f;
    p = fmaf(p, w, 1.4276565e-04f);
    p = fmaf(p, w, 1.9082604e-03f);
    p = fmaf(p, w, -5.1950124e-03f);
    p = fmaf(p, w, 8.1168916e-03f);
    p = fmaf(p, w, -1.0779791e-02f);
    p = fmaf(p, w, 1.3348577e-02f);
    p = fmaf(p, w, 1.4165810e+00f);
    p = fmaf(p, w, 4.0064324e+00f);
  }
  return p * u;
}

__global__ void HS_keys_kernel(uint2* __restrict__ ks) {
  const int t = threadIdx.x;
  if (t < NSAMP) {
    uint32_t a, b;
    tf2x32_full(0u, 1u, 0u, (uint32_t)t, a, b);  // split of key(1)
    ks[t] = make_uint2(a, b);
  }
}

__global__ __launch_bounds__(256, 6)
void HeteroscedasticSoftmax_kernel(const float* __restrict__ in,
                                   float* __restrict__ out,
                                   const uint2* __restrict__ keys) {
  __shared__ __half2 sls[NCH][256];  // (logit*log2e, std*log2e) f16x2

  const int t   = threadIdx.x;
  const int gid = blockIdx.x * 256 + t;
  const int b_  = gid >> 16;
  const int hw  = gid & 65535;

  const float L2E = 1.4426950408889634f;
  const float* pin = in + (size_t)b_ * (2 * NCH * HW) + hw;
  float acc[NCH];
#pragma unroll
  for (int c = 0; c < NCH; ++c) {
    float lg = pin[c * HW] * L2E;
    float sd = __expf(pin[(NCH + c) * HW]) * L2E;
    sls[c][t] = __floats2half2_rn(lg, sd);
    acc[c] = 0.0f;
  }
  __syncthreads();

  const uint32_t jbase = (uint32_t)(b_ * NCH) * (uint32_t)HW + (uint32_t)hw;

#pragma unroll 1
  for (int s = 0; s < NSAMP; ++s) {
    const uint2 kk = keys[s];
    const uint32_t k0 = __builtin_amdgcn_readfirstlane(kk.x);
    const uint32_t k1 = __builtin_amdgcn_readfirstlane(kk.y);
    const uint32_t k2 = k0 ^ k1 ^ 0x1BD11BDAu;

    float z[NCH];
#pragma unroll
    for (int c = 0; c < NCH; ++c) {
      const uint32_t bits = tf_fold(k0, k1, k2, jbase + (uint32_t)c * HW);
      const float eps = bits_to_eps(bits);
      const __half2 h = sls[c][t];
      z[c] = fmaf(eps, __high2float(h), __low2float(h));  // (lg + eps*sd)*log2e
    }

    float m0 = fmaxf(z[0], z[1]),  m1 = fmaxf(z[2], z[3]);
    float m2 = fmaxf(z[4], z[5]),  m3 = fmaxf(z[6], z[7]);
    float m4 = fmaxf(z[8], z[9]),  m5 = fmaxf(z[10], z[11]);
    float m6 = fmaxf(z[12], z[13]), m7 = fmaxf(z[14], z[15]);
    float m8 = fmaxf(z[16], z[17]);
    m0 = fmaxf(m0, m1); m2 = fmaxf(m2, m3); m4 = fmaxf(m4, m5);
    m6 = fmaxf(m6, m7); m8 = fmaxf(m8, z[18]);
    m0 = fmaxf(m0, m2); m4 = fmaxf(m4, m6);
    m0 = fmaxf(m0, m4);
    const float m = fmaxf(m0, m8);

#pragma unroll
    for (int c = 0; c < NCH; ++c) z[c] = __builtin_amdgcn_exp2f(z[c] - m);

    float s0 = z[0] + z[1],  s1 = z[2] + z[3];
    float s2 = z[4] + z[5],  s3 = z[6] + z[7];
    float s4 = z[8] + z[9],  s5 = z[10] + z[11];
    float s6 = z[12] + z[13], s7 = z[14] + z[15];
    float s8 = z[16] + z[17];
    s0 += s1; s2 += s3; s4 += s5; s6 += s7; s8 += z[18];
    s0 += s2; s4 += s6;
    s0 += s4;
    const float r = __builtin_amdgcn_rcpf(s0 + s8);

#pragma unroll
    for (int c = 0; c < NCH; ++c) acc[c] = fmaf(z[c], r, acc[c]);
  }

  float* pout = out + (size_t)b_ * (NCH * HW) + hw;
#pragma unroll
  for (int c = 0; c < NCH; ++c) pout[c * HW] = acc[c] * 0.01f;
}

extern "C" void kernel_launch(void* const* d_in, const int* in_sizes, int n_in,
                              void* d_out, int out_size, void* d_ws, size_t ws_size,
                              hipStream_t stream) {
  const float* in = (const float*)d_in[0];
  float* out = (float*)d_out;
  uint2* keys = (uint2*)d_ws;  // 800 B of scratch
  HS_keys_kernel<<<1, 128, 0, stream>>>(keys);
  HeteroscedasticSoftmax_kernel<<<2048, 256, 0, stream>>>(in, out, keys);
}